// Round 14
// baseline (305.234 us; speedup 1.0000x reference)
//
#include <hip/hip_runtime.h>
#include <math.h>

// B=4, TU=2048, TM=256, D=1024, H=16, DH=64, PAIRS=512
typedef unsigned short u16;
typedef __attribute__((ext_vector_type(8))) short bf16x8;
typedef __attribute__((ext_vector_type(4))) float f32x4;

__device__ __forceinline__ float sigmoidf_(float x) { return 1.0f / (1.0f + __expf(-x)); }
__device__ __forceinline__ u16 f2bf(float v) {
    union { float f; unsigned u; } x; x.f = v;
    unsigned r = x.u + 0x7fffu + ((x.u >> 16) & 1u);
    return (u16)(r >> 16);
}
__device__ __forceinline__ float bf2f(u16 u) {
    union { unsigned u; float f; } x; x.u = ((unsigned)u) << 16; return x.f;
}

#define GLD(src, dst) __builtin_amdgcn_global_load_lds( \
        (const __attribute__((address_space(1))) void*)(src), \
        (__attribute__((address_space(3))) void*)(dst), 16, 0, 0)
#define GLD4(src, dst) __builtin_amdgcn_global_load_lds( \
        (const __attribute__((address_space(1))) void*)(src), \
        (__attribute__((address_space(3))) void*)(dst), 4, 0, 0)

// ---------------------------------------------------------------------------
// balance_norm + gate + fused pairnorm, ONE WAVE PER ROW (shuffle-only).
// ---------------------------------------------------------------------------
__global__ void __launch_bounds__(256) norm_gate_kernel(
    const float* __restrict__ X,
    const float* __restrict__ w, const float* __restrict__ bvec,
    const float* __restrict__ bw_p,
    const float* __restrict__ gw, const float* __restrict__ gb_p,
    u16* __restrict__ OUT, u16* __restrict__ PN, float* __restrict__ G)
{
    const int row = blockIdx.x * 4 + (threadIdx.x >> 6);
    const int lane = threadIdx.x & 63;
    const float* xr = X + (size_t)row * 1024 + lane * 16;
    float4 xa = ((const float4*)xr)[0];
    float4 xb = ((const float4*)xr)[1];
    float4 xc = ((const float4*)xr)[2];
    float4 xd = ((const float4*)xr)[3];
    float s1 = (xa.x + xa.y + xa.z + xa.w) + (xb.x + xb.y + xb.z + xb.w)
             + (xc.x + xc.y + xc.z + xc.w) + (xd.x + xd.y + xd.z + xd.w);
    float s2 = xa.x * xa.x + xa.y * xa.y + xa.z * xa.z + xa.w * xa.w
             + xb.x * xb.x + xb.y * xb.y + xb.z * xb.z + xb.w * xb.w
             + xc.x * xc.x + xc.y * xc.y + xc.z * xc.z + xc.w * xc.w
             + xd.x * xd.x + xd.y * xd.y + xd.z * xd.z + xd.w * xd.w;
    #pragma unroll
    for (int o = 1; o <= 32; o <<= 1) s1 += __shfl_xor(s1, o);
    float h2 = s2;
    #pragma unroll
    for (int o = 1; o <= 16; o <<= 1) h2 += __shfl_xor(h2, o);
    const float oth = __shfl_xor(h2, 32);
    const float slo = (lane < 32) ? h2 : oth;
    const float shi = (lane < 32) ? oth : h2;
    const float mu = s1 * (1.0f / 1024.0f);
    const float var = (slo + shi) * (1.0f / 1024.0f) - mu * mu;
    const float rstd = rsqrtf(var + 1e-6f);
    const float imb = (slo - shi) * (1.0f / 512.0f) * (*bw_p);
    const float corr = (lane < 32) ? -imb : imb;
    const int i0 = lane * 16;
    const float4* wp = (const float4*)(w + i0);
    const float4* bp = (const float4*)(bvec + i0);
    const float4* gp = (const float4*)(gw + i0);
    float o16[16];
    float gd = 0.0f;
    #pragma unroll
    for (int q = 0; q < 4; ++q) {
        float4 xv = (q == 0) ? xa : (q == 1) ? xb : (q == 2) ? xc : xd;
        float4 wv = wp[q], bv = bp[q], gv = gp[q];
        float t0 = (xv.x - mu) * rstd * wv.x + bv.x + corr;
        float t1 = (xv.y - mu) * rstd * wv.y + bv.y + corr;
        float t2 = (xv.z - mu) * rstd * wv.z + bv.z + corr;
        float t3 = (xv.w - mu) * rstd * wv.w + bv.w + corr;
        gd += t0 * gv.x + t1 * gv.y + t2 * gv.z + t3 * gv.w;
        o16[4 * q + 0] = t0; o16[4 * q + 1] = t1; o16[4 * q + 2] = t2; o16[4 * q + 3] = t3;
    }
    #pragma unroll
    for (int o = 1; o <= 32; o <<= 1) gd += __shfl_xor(gd, o);
    if (lane == 0) G[row] = sigmoidf_(gd + *gb_p);
    u16 ob[16], pn[16];
    #pragma unroll
    for (int j = 0; j < 16; ++j) ob[j] = f2bf(o16[j]);
    #pragma unroll
    for (int j = 0; j < 8; ++j) {
        float px = o16[2 * j] + 1e-8f, py = o16[2 * j + 1] + 1e-8f;
        float rr = rsqrtf(px * px + py * py);
        pn[2 * j] = f2bf(px * rr); pn[2 * j + 1] = f2bf(py * rr);
    }
    *(uint4*)(OUT + (size_t)row * 1024 + i0) = *(uint4*)ob;
    *(uint4*)(OUT + (size_t)row * 1024 + i0 + 8) = *(uint4*)(ob + 8);
    *(uint4*)(PN + (size_t)row * 1024 + i0) = *(uint4*)pn;
    *(uint4*)(PN + (size_t)row * 1024 + i0 + 8) = *(uint4*)(pn + 8);
}

// ---------------------------------------------------------------------------
// weight fp32 -> bf16 (8 slots of 1M elements; order set by pointer args)
// ---------------------------------------------------------------------------
__global__ void __launch_bounds__(256) wconv_kernel(
    const float* w0, const float* w1, const float* w2, const float* w3,
    const float* w4, const float* w5, const float* w6, const float* w7,
    u16* __restrict__ dst)
{
    const float* s;
    switch (blockIdx.y) {
        case 0: s = w0; break; case 1: s = w1; break;
        case 2: s = w2; break; case 3: s = w3; break;
        case 4: s = w4; break; case 5: s = w5; break;
        case 6: s = w6; break; default: s = w7; break;
    }
    long i = (long)blockIdx.x * 1024 + threadIdx.x * 4;
    float4 v = *(const float4*)(s + i);
    u16 o[4] = { f2bf(v.x), f2bf(v.y), f2bf(v.z), f2bf(v.w) };
    *(uint2*)(dst + (long)blockIdx.y * 1048576 + i) = *(uint2*)o;
}

// ---------------------------------------------------------------------------
// FUSED FLASH ATTENTION (unchanged — verified passing).
// ---------------------------------------------------------------------------
__global__ void __launch_bounds__(256) attn_flash(
    const u16* __restrict__ Q, const u16* __restrict__ K,
    const u16* __restrict__ VT, const float* __restrict__ AG,
    const float* __restrict__ EG, u16* __restrict__ OC,
    int TQ, int TKV, long vbs)
{
    __shared__ __align__(16) u16 shm[21504];
    float* egf = (float*)(shm + 20480);
    const int t = threadIdx.x;
    const int lane = t & 63, w = t >> 6;
    const int l15 = lane & 15, g = lane >> 4;
    const int qt = blockIdx.x, h = blockIdx.y, b = blockIdx.z;
    const long qrow = (long)b * TQ + qt * 64 + w * 16 + l15;
    const u16* Qp = Q + qrow * 1024 + h * 64 + g * 8;
    const bf16x8 qf0 = *(const bf16x8*)(Qp);
    const bf16x8 qf1 = *(const bf16x8*)(Qp + 32);
    const u16* Kp = K + ((long)b * TKV + w * 16 + l15) * 1024 + h * 64 + g * 8;
    const u16* Vp = VT + (long)b * vbs + (long)(h * 64 + w * 16 + l15) * TKV + g * 8;
    const float* egp = EG + (long)b * TKV + lane;

    auto stage = [&](int kvt, int buf) {
        GLD(Kp + (long)kvt * 1024,      shm + buf * 4096 + (w * 2 + 0) * 512);
        GLD(Kp + (long)kvt * 1024 + 32, shm + buf * 4096 + (w * 2 + 1) * 512);
        GLD(Vp + kvt,      shm + 8192 + buf * 4096 + (w * 2 + 0) * 512);
        GLD(Vp + kvt + 32, shm + 8192 + buf * 4096 + (w * 2 + 1) * 512);
        GLD4(egp + kvt, egf + (buf * 4 + w) * 64);
    };

    const int nT = TKV >> 6;
    f32x4 O[4] = {};
    float mrun = -3.0e38f, lrun = 0.0f, serun = 0.0f;
    stage(0, 0);
    for (int i = 0; i < nT; ++i) {
        const int buf = i & 1;
        if (i + 1 < nT) {
            stage((i + 1) << 6, buf ^ 1);
            asm volatile("s_waitcnt vmcnt(5)" ::: "memory");
        } else {
            asm volatile("s_waitcnt vmcnt(0)" ::: "memory");
        }
        __builtin_amdgcn_sched_barrier(0);
        __builtin_amdgcn_s_barrier();
        const u16* kb = shm + buf * 4096;
        const u16* vb = shm + 8192 + buf * 4096;
        f32x4 sa[4] = {};
        #pragma unroll
        for (int kvf = 0; kvf < 4; ++kvf) {
            bf16x8 kf = *(const bf16x8*)(kb + (kvf * 2 + 0) * 512 + lane * 8);
            sa[kvf] = __builtin_amdgcn_mfma_f32_16x16x32_bf16(kf, qf0, sa[kvf], 0, 0, 0);
        }
        #pragma unroll
        for (int kvf = 0; kvf < 4; ++kvf) {
            bf16x8 kf = *(const bf16x8*)(kb + (kvf * 2 + 1) * 512 + lane * 8);
            sa[kvf] = __builtin_amdgcn_mfma_f32_16x16x32_bf16(kf, qf1, sa[kvf], 0, 0, 0);
        }
        float ev[4][4];
        float tmax = -3.0e38f;
        #pragma unroll
        for (int kvf = 0; kvf < 4; ++kvf)
            #pragma unroll
            for (int j = 0; j < 4; ++j) {
                float s = sa[kvf][j] * 0.125f;
                ev[kvf][j] = s;
                tmax = fmaxf(tmax, s);
            }
        tmax = fmaxf(tmax, __shfl_xor(tmax, 16));
        tmax = fmaxf(tmax, __shfl_xor(tmax, 32));
        const float mnew = fmaxf(mrun, tmax);
        const float corr = __expf(mrun - mnew);
        mrun = mnew;
        float suml = 0.0f, sumg = 0.0f;
        unsigned pk[4][2];
        #pragma unroll
        for (int kvf = 0; kvf < 4; ++kvf) {
            float4 eg4 = *(const float4*)(egf + (buf * 4 + w) * 64 + kvf * 16 + 4 * g);
            float e0 = __expf(ev[kvf][0] - mnew);
            float e1 = __expf(ev[kvf][1] - mnew);
            float e2 = __expf(ev[kvf][2] - mnew);
            float e3 = __expf(ev[kvf][3] - mnew);
            suml += (e0 + e1) + (e2 + e3);
            float g0 = e0 * eg4.x, g1 = e1 * eg4.y, g2 = e2 * eg4.z, g3 = e3 * eg4.w;
            sumg += (g0 + g1) + (g2 + g3);
            pk[kvf][0] = (unsigned)f2bf(g0) | ((unsigned)f2bf(g1) << 16);
            pk[kvf][1] = (unsigned)f2bf(g2) | ((unsigned)f2bf(g3) << 16);
        }
        suml += __shfl_xor(suml, 16); suml += __shfl_xor(suml, 32);
        sumg += __shfl_xor(sumg, 16); sumg += __shfl_xor(sumg, 32);
        lrun = lrun * corr + suml;
        serun = serun * corr + sumg;
        #pragma unroll
        for (int fd = 0; fd < 4; ++fd)
            #pragma unroll
            for (int j = 0; j < 4; ++j) O[fd][j] *= corr;
        u16* pw = shm + 16384 + w * 1024;
        #pragma unroll
        for (int kvf = 0; kvf < 4; ++kvf) {
            const int base = (kvf >> 1) * 512
                           + (l15 + 16 * (2 * (kvf & 1) + (g >> 1))) * 8
                           + 4 * (g & 1);
            *(unsigned*)(pw + base) = pk[kvf][0];
            *(unsigned*)(pw + base + 2) = pk[kvf][1];
        }
        #pragma unroll
        for (int ksv = 0; ksv < 2; ++ksv) {
            bf16x8 pf = *(const bf16x8*)(pw + ksv * 512 + lane * 8);
            #pragma unroll
            for (int fd = 0; fd < 4; ++fd) {
                bf16x8 vf = *(const bf16x8*)(vb + (fd * 2 + ksv) * 512 + lane * 8);
                O[fd] = __builtin_amdgcn_mfma_f32_16x16x32_bf16(vf, pf, O[fd], 0, 0, 0);
            }
        }
        if (i + 1 < nT) __builtin_amdgcn_s_barrier();
    }
    const float agv = AG[qrow];
    const float fac = agv / (agv * serun + lrun * 1e-8f);
    __syncthreads();
    u16* tw = shm + w * 1152;
    #pragma unroll
    for (int fd = 0; fd < 4; ++fd) {
        const int d0 = fd * 16 + 4 * g;
        unsigned v01 = (unsigned)f2bf(O[fd][0] * fac) | ((unsigned)f2bf(O[fd][1] * fac) << 16);
        unsigned v23 = (unsigned)f2bf(O[fd][2] * fac) | ((unsigned)f2bf(O[fd][3] * fac) << 16);
        *(unsigned*)(tw + l15 * 72 + d0) = v01;
        *(unsigned*)(tw + l15 * 72 + d0 + 2) = v23;
    }
    const int qr = lane >> 2, part = lane & 3;
    uint4 va = *(const uint4*)(tw + qr * 72 + part * 16);
    uint4 vb2 = *(const uint4*)(tw + qr * 72 + part * 16 + 8);
    u16* op = OC + ((long)b * TQ + qt * 64 + w * 16 + qr) * 1024 + h * 64 + part * 16;
    *(uint4*)(op) = va;
    *(uint4*)(op + 8) = vb2;
}

// ---------------------------------------------------------------------------
// mfma256: 256x256 bf16 NT GEMM, 8-phase Gray-code operand-reuse schedule.
// (unchanged from round 13 — only <256,6> instantiated now)
// ---------------------------------------------------------------------------
#define RD_A(BUF, MQ) do { \
    _Pragma("unroll") for (int fr_ = 0; fr_ < 4; ++fr_) \
    _Pragma("unroll") for (int kk_ = 0; kk_ < 2; ++kk_) \
        af[fr_][kk_] = *(const bf16x8*)(sh + (BUF) * BUFSZ + (MQ) * 8192 + (wm * 4 + fr_) * 1024 + kk_ * 512 + lane * 8); \
} while (0)
#define RD_B(BUF, NQ, DST) do { \
    _Pragma("unroll") for (int fc_ = 0; fc_ < NRC; ++fc_) \
    _Pragma("unroll") for (int kk_ = 0; kk_ < 2; ++kk_) \
        DST[fc_][kk_] = *(const bf16x8*)(sh + (BUF) * BUFSZ + 16384 + (NQ) * BHALF + (wn * NRC + fc_) * 1024 + kk_ * 512 + lane * 8); \
} while (0)
#define MM(SRC, MQ, NQ) do { \
    __builtin_amdgcn_s_setprio(1); \
    _Pragma("unroll") for (int fr_ = 0; fr_ < 4; ++fr_) \
    _Pragma("unroll") for (int fc_ = 0; fc_ < NRC; ++fc_) \
    _Pragma("unroll") for (int kk_ = 0; kk_ < 2; ++kk_) \
        acc[(MQ) * 4 + fr_][(NQ) * NRC + fc_] = __builtin_amdgcn_mfma_f32_16x16x32_bf16( \
            af[fr_][kk_], SRC[fc_][kk_], acc[(MQ) * 4 + fr_][(NQ) * NRC + fc_], 0, 0, 0); \
    __builtin_amdgcn_s_setprio(0); \
} while (0)
#define FENCE1() do { \
    __builtin_amdgcn_s_barrier(); \
    asm volatile("s_waitcnt lgkmcnt(0)" ::: "memory"); \
    __builtin_amdgcn_sched_barrier(0); \
} while (0)
#define FENCE2(VM) do { \
    __builtin_amdgcn_sched_barrier(0); \
    if ((VM) == 1) { \
        if constexpr (BN == 256) asm volatile("s_waitcnt vmcnt(8)" ::: "memory"); \
        else                     asm volatile("s_waitcnt vmcnt(6)" ::: "memory"); \
    } else if ((VM) == 2) { asm volatile("s_waitcnt vmcnt(0)" ::: "memory"); } \
    __builtin_amdgcn_s_barrier(); \
} while (0)

template<int BN, int EPI>
__global__ void __launch_bounds__(512, 1) mfma256(
    const u16* __restrict__ A, const u16* __restrict__ B,
    void* __restrict__ C, void* __restrict__ Cx, void* __restrict__ Cy,
    int K, int lda, int ldb,
    const float* __restrict__ base, const float* __restrict__ rs)
{
    constexpr int NRC = BN / 128;
    constexpr int BHALF = BN * 32;
    constexpr int BUFSZ = 16384 + 2 * BHALF;
    extern __shared__ u16 sh[];
    const int gx = gridDim.x, gy = gridDim.y;
    const int lin = blockIdx.x + gx * blockIdx.y;
    const int xcd = lin & 7, off = lin >> 3;
    const int lby = gy >> 3;
    const int by = xcd * lby + (off % lby);
    const int bx = off / lby;
    const int t = threadIdx.x;
    const int lane = t & 63, w = t >> 6;
    const int wm = w >> 2, wn = w & 3;
    const long m0 = (long)by * 256;
    const long n0 = (long)bx * BN;
    const int l15 = lane & 15, g = lane >> 4;

    auto stageA = [&](int h, int kt, int buf) {
        const long kb = (long)kt * 64 + g * 8;
        #pragma unroll
        for (int r2 = 0; r2 < 2; ++r2) {
            const int c = w + 8 * r2;
            const int sub = c >> 1, kc = c & 1;
            GLD(A + (m0 + h * 128 + sub * 16 + l15) * lda + kb + kc * 32,
                sh + buf * BUFSZ + h * 8192 + c * 512);
        }
    };
    auto stageB = [&](int h, int kt, int buf) {
        const long kb = (long)kt * 64 + g * 8;
        if constexpr (BN == 256) {
            #pragma unroll
            for (int r2 = 0; r2 < 2; ++r2) {
                const int c = w + 8 * r2;
                const int sub = c >> 1, kc = c & 1;
                GLD(B + (n0 + h * 128 + sub * 16 + l15) * ldb + kb + kc * 32,
                    sh + buf * BUFSZ + 16384 + h * BHALF + c * 512);
            }
        } else {
            const int c = w;
            const int sub = c >> 1, kc = c & 1;
            GLD(B + (n0 + h * 64 + sub * 16 + l15) * ldb + kb + kc * 32,
                sh + buf * BUFSZ + 16384 + h * BHALF + c * 512);
        }
    };

    const int nIter = K >> 7;
    f32x4 acc[8][2 * NRC] = {};
    bf16x8 af[4][2], bf0[NRC][2], bf1[NRC][2];

    stageA(0, 0, 0); stageA(1, 0, 0); stageB(0, 0, 0); stageB(1, 0, 0);
    stageA(0, 1, 1); stageA(1, 1, 1); stageB(0, 1, 1); stageB(1, 1, 1);
    if constexpr (BN == 256) asm volatile("s_waitcnt vmcnt(8)" ::: "memory");
    else                     asm volatile("s_waitcnt vmcnt(6)" ::: "memory");
    __builtin_amdgcn_sched_barrier(0);
    __builtin_amdgcn_s_barrier();

    for (int i = 0; i < nIter; ++i) {
        const bool pre = (i + 1 < nIter);
        const int ktA = 2 * i + 2, ktB = 2 * i + 3;
        RD_A(0, 0); RD_B(0, 0, bf0);
        FENCE1(); MM(bf0, 0, 0); FENCE2(0);
        RD_B(0, 1, bf1);
        if (pre) { stageA(0, ktA, 0); stageB(0, ktA, 0); }
        FENCE1(); MM(bf1, 0, 1); FENCE2(0);
        RD_A(0, 1);
        if (pre) stageB(1, ktA, 0);
        FENCE1(); MM(bf1, 1, 1); FENCE2(0);
        if (pre) stageA(1, ktA, 0);
        FENCE1(); MM(bf0, 1, 0); FENCE2(pre ? 1 : 2);
        RD_A(1, 0); RD_B(1, 0, bf0);
        FENCE1(); MM(bf0, 0, 0); FENCE2(0);
        RD_B(1, 1, bf1);
        if (pre) { stageA(0, ktB, 1); stageB(0, ktB, 1); }
        FENCE1(); MM(bf1, 0, 1); FENCE2(0);
        RD_A(1, 1);
        if (pre) stageB(1, ktB, 1);
        FENCE1(); MM(bf1, 1, 1); FENCE2(0);
        if (pre) stageA(1, ktB, 1);
        FENCE1(); MM(bf0, 1, 0); FENCE2(pre ? 1 : 0);
    }

    #pragma unroll
    for (int mq = 0; mq < 2; ++mq)
    #pragma unroll
    for (int fr = 0; fr < 4; ++fr)
    #pragma unroll
    for (int nq = 0; nq < 2; ++nq)
    #pragma unroll
    for (int fc = 0; fc < NRC; ++fc) {
        const long grow0 = m0 + mq * 128 + wm * 64 + fr * 16 + g * 4;
        const long gcol = n0 + nq * (BN / 2) + wn * (16 * NRC) + fc * 16 + l15;
        const f32x4 a = acc[mq * 4 + fr][nq * NRC + fc];
        if constexpr (EPI == 3) {
            #pragma unroll
            for (int j = 0; j < 4; ++j) {
                const long idx = (grow0 + j) * 1024 + gcol;
                ((float*)C)[idx] = base[idx] + a[j] * rs[grow0 + j];
            }
        } else {  // EPI == 6
            const int sec = (int)(n0 >> 10);
            if (sec == 0) {
                #pragma unroll
                for (int j = 0; j < 4; ++j)
                    ((u16*)C)[(grow0 + j) * 1024 + gcol] = f2bf(a[j]);       // K_conv
            } else if (sec == 1) {
                const long col = gcol - 1024;
                u16 pk[4] = { f2bf(a[0]), f2bf(a[1]), f2bf(a[2]), f2bf(a[3]) };
                const long idx = (grow0 >> 11) * 2097152 + col * 2048 + (grow0 & 2047);
                *(uint2*)&((u16*)Cx)[idx] = *(uint2*)pk;                      // VT_conv
            } else {
                #pragma unroll
                for (int j = 0; j < 4; ++j)
                    ((u16*)Cy)[(grow0 + j) * 1024 + (gcol - 2048)] = f2bf(a[j]); // Q_emer
            }
        }
    }
}
#undef RD_A
#undef RD_B
#undef MM
#undef FENCE1
#undef FENCE2

// ---------------------------------------------------------------------------
// bf16 NT MFMA GEMM, 128xBN tile, 256 threads, ring-3.
// EPI 5 now does the OT (transposed) side via LDS transpose -> coalesced
// float4 accB reads + OT writes (was scalar-scattered, ~16x amplification).
// ---------------------------------------------------------------------------
template<int BN, int EPI, bool SWZ>
__global__ void __launch_bounds__(256) mfma_nt(
    const u16* __restrict__ A, long zAb, long zAh,
    const u16* __restrict__ B, long zBb, long zBh,
    void* __restrict__ C, long zCb, long zCh,
    void* __restrict__ Cx, void* __restrict__ Cy,
    int K, int lda, int ldb, int ldc, float alpha, int nH, int nsplit,
    const float* __restrict__ base, const float* __restrict__ rs,
    const float* __restrict__ accB, float* __restrict__ OT,
    long zOT, int ldt)
{
    constexpr int NR = BN / 32;
    constexpr int ABUF = 128 * 32;
    constexpr int BBUF = BN * 32;
    __shared__ __align__(16) u16 sh[3 * (ABUF + BBUF)];
    u16* const Ab0 = sh;
    u16* const Bb0 = sh + 3 * ABUF;
    int bx, by, bz;
    if constexpr (SWZ) {
        const int gx = gridDim.x, gy = gridDim.y;
        const int lin = blockIdx.x + gx * blockIdx.y;
        const int xcd = lin & 7, c = lin >> 3;
        const int LBY = gy >> 3;
        const int SPB = 4 * LBY;
        const int sc = c / SPB, rr = c - sc * SPB;
        const int byl = rr >> 2, bxl = rr & 3;
        by = xcd * LBY + byl;
        bx = sc * 4 + bxl;
        bz = 0;
    } else {
        bx = blockIdx.x; by = blockIdx.y; bz = blockIdx.z;
    }
    const int t = threadIdx.x;
    const int lane = t & 63, w = t >> 6;
    const int wr = w >> 1, wc = w & 1;
    const int slab = bz / nsplit, ks = bz - slab * nsplit;
    const int b = slab / nH, h = slab - b * nH;
    const int kchunk = K / nsplit;
    const int kbeg = ks * kchunk, kend = kbeg + kchunk;
    const long m0 = (long)by * 128;
    const long n0 = (long)bx * BN;
    const int frow = lane & 15, fko = (lane >> 4) * 8;
    const u16* gaA = A + zAb * b + zAh * h + (m0 + 32 * w + frow) * lda + fko;
    const u16* gbB;
    if constexpr (BN == 128) gbB = B + zBb * b + zBh * h + (n0 + 32 * w + frow) * ldb + fko;
    else                     gbB = B + zBb * b + zBh * h + (n0 + 16 * w + frow) * ldb + fko;

    auto stage = [&](int kk, int p) {
        u16* ap = Ab0 + p * ABUF;
        u16* bp = Bb0 + p * BBUF;
        GLD(gaA + kk, ap + 2 * w * 512);
        GLD(gaA + 16L * lda + kk, ap + (2 * w + 1) * 512);
        if constexpr (BN == 128) {
            GLD(gbB + kk, bp + 2 * w * 512);
            GLD(gbB + 16L * ldb + kk, bp + (2 * w + 1) * 512);
        } else {
            GLD(gbB + kk, bp + w * 512);
        }
    };

    const int nIter = (kend - kbeg) >> 5;
    f32x4 acc[4][NR] = {};
    stage(kbeg, 0);
    if (nIter > 1) stage(kbeg + 32, 1);
    int cur = 0;
    for (int i = 0; i < nIter; ++i) {
        if (i + 2 < nIter) {
            int p2 = cur + 2; if (p2 >= 3) p2 -= 3;
            stage(kbeg + (i + 2) * 32, p2);
            if constexpr (BN == 128) asm volatile("s_waitcnt vmcnt(8)" ::: "memory");
            else                     asm volatile("s_waitcnt vmcnt(6)" ::: "memory");
        } else if (i + 1 < nIter) {
            if constexpr (BN == 128) asm volatile("s_waitcnt vmcnt(4)" ::: "memory");
            else                     asm volatile("s_waitcnt vmcnt(3)" ::: "memory");
        } else {
            asm volatile("s_waitcnt vmcnt(0)" ::: "memory");
        }
        __builtin_amdgcn_sched_barrier(0);
        __builtin_amdgcn_s_barrier();
        __builtin_amdgcn_sched_barrier(0);
        const u16* ap = Ab0 + cur * ABUF;
        const u16* bp = Bb0 + cur * BBUF;
        bf16x8 af[4], bfr[NR];
        #pragma unroll
        for (int m = 0; m < 4; ++m)
            af[m] = *(const bf16x8*)(ap + (wr * 4 + m) * 512 + lane * 8);
        #pragma unroll
        for (int n = 0; n < NR; ++n)
            bfr[n] = *(const bf16x8*)(bp + (wc * NR + n) * 512 + lane * 8);
        asm volatile("s_waitcnt lgkmcnt(0)" ::: "memory");
        __builtin_amdgcn_sched_barrier(0);
        __builtin_amdgcn_s_barrier();
        #pragma unroll
        for (int m = 0; m < 4; ++m)
            #pragma unroll
            for (int n = 0; n < NR; ++n)
                acc[m][n] = __builtin_amdgcn_mfma_f32_16x16x32_bf16(af[m], bfr[n], acc[m][n], 0, 0, 0);
        cur = (cur == 2) ? 0 : cur + 1;
    }
    const long Coff = zCb * b + zCh * h;
    const int l15 = lane & 15, l4 = lane >> 4;
    #pragma unroll
    for (int m = 0; m < 4; ++m) {
        #pragma unroll
        for (int n = 0; n < NR; ++n) {
            #pragma unroll
            for (int j = 0; j < 4; ++j) {
                const long grow = m0 + wr * 64 + m * 16 + l4 * 4 + j;
                const long gcol = n0 + wc * (BN / 2) + n * 16 + l15;
                const float v = acc[m][n][j] * alpha;
                if constexpr (EPI == 3) {
                    const long idx = grow * ldc + gcol;
                    ((float*)C)[idx] = base[idx] + v * rs[grow];
                } else if constexpr (EPI == 5) {
                    const long idx = Coff + grow * ldc + gcol;
                    ((float*)C)[idx] = 0.7f * base[idx] + 0.3f * v;
                } else if constexpr (EPI == 7) {
                    const int sec = (int)(n0 >> 10);
                    if (sec == 0) ((u16*)C)[grow * 1024 + gcol] = f2bf(v);            // Q_conv
                    else if (sec == 1) ((u16*)Cx)[grow * 1024 + (gcol - 1024)] = f2bf(v); // K_emer
                    else {
                        const long col = gcol - 2048;                                  // VT_emer
                        ((u16*)Cy)[(grow >> 8) * 262144 + col * 256 + (grow & 255)] = f2bf(v);
                    }
                }
            }
        }
    }
    if constexpr (EPI == 5) {
        // OT[n0+k][m0+q] = 0.7*accB + 0.3*(alpha*acc) via LDS transpose:
        // coalesced accB reads and OT float4 writes (row = k, 512B contiguous).
        float* tf = (float*)sh;                 // 64 x 132 f32 = 33.8 KB < 48 KB
        __syncthreads();
        #pragma unroll
        for (int h2 = 0; h2 < 2; ++h2) {
            if (wc == h2) {
                #pragma unroll
                for (int m = 0; m < 4; ++m)
                    #pragma unroll
                    for (int n = 0; n < NR; ++n)
                        #pragma unroll
                        for (int j = 0; j < 4; ++j)
                            tf[(n * 16 + l15) * 132 + wr * 64 + m * 16 + l4 * 4 + j]
                                = alpha * acc[m][n][j];
            }
            __syncthreads();
            const int r0 = t >> 5, q4 = (t & 31) * 4;
            #pragma unroll
            for (int ri = 0; ri < 8; ++ri) {
                const int row = r0 + 8 * ri;
                const long kglob = n0 + h2 * 64 + row;
                const long obase = zOT * b + kglob * (long)ldt + m0 + q4;
                float4 v4 = *(float4*)&tf[row * 132 + q4];
                float4 a4 = *(const float4*)&accB[obase];
                float4 o4;
                o4.x = 0.7f * a4.x + 0.3f * v4.x;
                o4.y = 0.7f * a4.y + 0.3f * v4.y;
                o4.z = 0.7f * a4.z + 0.3f * v4.z;
                o4.w = 0.7f * a4.w + 0.3f * v4.w;
                *(float4*)&OT[obase] = o4;
            }
            if (h2 == 0) __syncthreads();
        }
    }
}

__global__ void __launch_bounds__(256) rowmean_sig_kernel(
    const float* __restrict__ X, int len, float invlen,
    const float* __restrict__ alpha_p, float* __restrict__ OUT)
{
    const int row = blockIdx.x * 4 + (threadIdx.x >> 6);
    const int lane = threadIdx.x & 63;
    const float* xr = X + (long)row * len;
    float s = 0.0f;
    for (int k = lane; k < len; k += 64) s += xr[k];
    for (int o = 32; o > 0; o >>= 1) s += __shfl_xor(s, o);
    if (lane == 0) OUT[row] = sigmoidf_((*alpha_p) * s * invlen);
}

#define MFMA_TAIL nullptr, nullptr, nullptr, nullptr, 0L, 0

extern "C" void kernel_launch(void* const* d_in, const int* in_sizes, int n_in,
                              void* d_out, int out_size, void* d_ws, size_t ws_size,
                              hipStream_t stream)
{
    (void)in_sizes; (void)n_in; (void)out_size; (void)ws_size;
    const float* o_micro    = (const float*)d_in[0];
    const float* o_macro    = (const float*)d_in[1];
    const float* r_conv_acc = (const float*)d_in[2];
    const float* r_emer_acc = (const float*)d_in[3];
    const float* ln_u_w = (const float*)d_in[4];
    const float* ln_u_b = (const float*)d_in[5];
    const float* bw_u   = (const float*)d_in[6];
    const float* ln_m_w = (const float*)d_in[7];
    const float* ln_m_b = (const float*)d_in[8];
    const float* bw_m   = (const float*)d_in[9];
    const float* gu_w   = (const float*)d_in[10];
    const float* gu_b   = (const float*)d_in[11];
    const float* gm_w   = (const float*)d_in[12];
    const float* gm_b   = (const float*)d_in[13];
    const float* wq_c   = (const float*)d_in[14];
    const float* wk_c   = (const float*)d_in[15];
    const float* wv_c   = (const float*)d_in[16];
    const float* wo_c   = (const float*)d_in[17];
    const float* wq_e   = (const float*)d_in[18];
    const float* wk_e   = (const float*)d_in[19];
    const float* wv_e   = (const float*)d_in[20];
    const float* wo_e   = (const float*)d_in[21];
    const float* res_alpha = (const float*)d_in[22];

    float* out = (float*)d_out;
    float* out_micro = out;              // (4,2048,1024)
    float* out_macro = out + 8388608;    // (4,256,1024)
    float* out_rconv = out + 9437184;    // (4,256,2048)
    float* out_remer = out + 11534336;   // (4,2048,256)

    // workspace (f32 slot offsets; bf16 buffers use 2 el/slot)
    float* ws = (float*)d_ws;
    u16* OUb = (u16*)ws;                       // 8388608 bf16 (normed micro)
    u16* OMb = (u16*)(ws + 4194304);           // 1048576 bf16 (normed macro)
    u16* WB  = (u16*)(ws + 4718592);           // 8 x 1048576 bf16 weights
                                               //   [wk_c wv_c wq_e | wq_c wk_e wv_e | wo_c wo_e]
    u16* Kcb = (u16*)(ws + 8912896);           // conv K (8192x1024) -> later CTe
    u16* VTc = (u16*)(ws + 13107200);          // conv V^T [b][h][64][2048]
    u16* Qeb = (u16*)(ws + 17301504);          // emer Q (8192x1024)
    u16* Qcb = (u16*)(ws + 21495808);          // conv Q (1024x1024)
    u16* Keb = (u16*)(ws + 22020096);          // emer K (1024x1024)
    u16* VTe = (u16*)(ws + 22544384);          // emer V^T [b][h][64][256]
    u16* PNu = (u16*)(ws + 23068672);          // pairnormed micro (8.4M bf16)
    float* CT = ws + 27262976;                 // early: PNm; later conv ctx bf16
    float* GU = ws + 28311552;                 // 8192
    float* GM = GU + 8192;                     // 1024
    float* RCS = GM + 1024;                    // 1024
    float* RES = RCS + 1024;                   // 8192
    u16* PNm = (u16*)CT;
    u16* CTc = (u16*)CT;                       // conv ctx bf16 (1024x1024)
    u16* CTe = Kcb;                            // emer ctx bf16 (8192x1024)

    // 1. weights -> bf16, reordered for fused projections
    wconv_kernel<<<dim3(1024, 8), 256, 0, stream>>>(wk_c, wv_c, wq_e, wq_c, wk_e, wv_e, wo_c, wo_e, WB);
    // 2. balance norms + gates + fused pairnorm (wave-per-row)
    norm_gate_kernel<<<2048, 256, 0, stream>>>(o_micro, ln_u_w, ln_u_b, bw_u, gu_w, gu_b, OUb, PNu, GU);
    norm_gate_kernel<<<256, 256, 0, stream>>>(o_macro, ln_m_w, ln_m_b, bw_m, gm_w, gm_b, OMb, PNm, GM);
    // 3. resonance GEMM + 0.7/0.3 blend; OT side via LDS-transposed coalesced writes
    mfma_nt<128, 5, false><<<dim3(16, 2, 4), 256, 0, stream>>>(
        PNm, 262144L, 0L, PNu, 2097152L, 0L, out_rconv, 524288L, 0L, nullptr, nullptr,
        1024, 1024, 1024, 2048, 1.0f / 512.0f, 1, 1,
        r_conv_acc, nullptr, r_emer_acc, out_remer, 524288L, 256);
    // 4. resonance scalars
    rowmean_sig_kernel<<<256, 256, 0, stream>>>(out_rconv, 2048, 1.0f / 2048.0f, res_alpha, RCS);
    rowmean_sig_kernel<<<2048, 256, 0, stream>>>(out_remer, 256, 1.0f / 256.0f, res_alpha, RES);
    // 5. fused micro-side projections: [K_conv | VT_conv | Q_emer]  (8-phase + reuse)
    mfma256<256, 6><<<dim3(12, 32), 512, 131072, stream>>>(
        OUb, WB, Kcb, VTc, Qeb, 1024, 1024, 1024, nullptr, nullptr);
    // 6. fused macro-side projections: [Q_conv | K_emer | VT_emer]
    mfma_nt<128, 7, true><<<dim3(24, 8, 1), 256, 0, stream>>>(
        OMb, 0L, 0L, WB + 3 * 1048576, 0L, 0L, Qcb, 0L, 0L, Keb, VTe,
        1024, 1024, 1024, 1024, 1.0f, 1, 1, MFMA_TAIL);
    // 7. conv fused flash attention (q from macro, kv from micro)
    attn_flash<<<dim3(4, 16, 4), 256, 0, stream>>>(
        Qcb, Kcb, VTc, GM, GU, CTc, 256, 2048, 2097152L);
    // 8. conv out-proj + residual + r_conv_scalar -> o_macro_new
    mfma_nt<128, 3, false><<<dim3(8, 8, 1), 256, 0, stream>>>(
        CTc, 0L, 0L, WB + 6 * 1048576, 0L, 0L, out_macro, 0L, 0L, nullptr, nullptr,
        1024, 1024, 1024, 1024, 1.0f, 1, 1, o_macro, RCS, nullptr, nullptr, 0L, 0);
    // 9. emer fused flash attention (q from micro, kv from macro)
    attn_flash<<<dim3(32, 16, 4), 256, 0, stream>>>(
        Qeb, Keb, VTe, GU, GM, CTe, 2048, 256, 262144L);
    // 10. emer out-proj + residual + r_emer_scalar -> o_micro_new
    //     (ring-3 mfma_nt, 512 blocks ~3/CU — round-7-proven path)
    mfma_nt<128, 3, true><<<dim3(8, 64, 1), 256, 0, stream>>>(
        CTe, 0L, 0L, WB + 7 * 1048576, 0L, 0L, out_micro, 0L, 0L, nullptr, nullptr,
        1024, 1024, 1024, 1024, 1.0f, 1, 1, o_micro, RES, nullptr, nullptr, 0L, 0);
}

// Round 15
// 297.181 us; speedup vs baseline: 1.0271x; 1.0271x over previous
//
#include <hip/hip_runtime.h>
#include <math.h>

// B=4, TU=2048, TM=256, D=1024, H=16, DH=64, PAIRS=512
typedef unsigned short u16;
typedef __attribute__((ext_vector_type(8))) short bf16x8;
typedef __attribute__((ext_vector_type(4))) float f32x4;

__device__ __forceinline__ float sigmoidf_(float x) { return 1.0f / (1.0f + __expf(-x)); }
__device__ __forceinline__ u16 f2bf(float v) {
    union { float f; unsigned u; } x; x.f = v;
    unsigned r = x.u + 0x7fffu + ((x.u >> 16) & 1u);
    return (u16)(r >> 16);
}
__device__ __forceinline__ float bf2f(u16 u) {
    union { unsigned u; float f; } x; x.u = ((unsigned)u) << 16; return x.f;
}

#define GLD(src, dst) __builtin_amdgcn_global_load_lds( \
        (const __attribute__((address_space(1))) void*)(src), \
        (__attribute__((address_space(3))) void*)(dst), 16, 0, 0)
#define GLD4(src, dst) __builtin_amdgcn_global_load_lds( \
        (const __attribute__((address_space(1))) void*)(src), \
        (__attribute__((address_space(3))) void*)(dst), 4, 0, 0)

// ---------------------------------------------------------------------------
// balance_norm + gate + fused pairnorm, ONE WAVE PER ROW (shuffle-only).
// ---------------------------------------------------------------------------
__global__ void __launch_bounds__(256) norm_gate_kernel(
    const float* __restrict__ X,
    const float* __restrict__ w, const float* __restrict__ bvec,
    const float* __restrict__ bw_p,
    const float* __restrict__ gw, const float* __restrict__ gb_p,
    u16* __restrict__ OUT, u16* __restrict__ PN, float* __restrict__ G)
{
    const int row = blockIdx.x * 4 + (threadIdx.x >> 6);
    const int lane = threadIdx.x & 63;
    const float* xr = X + (size_t)row * 1024 + lane * 16;
    float4 xa = ((const float4*)xr)[0];
    float4 xb = ((const float4*)xr)[1];
    float4 xc = ((const float4*)xr)[2];
    float4 xd = ((const float4*)xr)[3];
    float s1 = (xa.x + xa.y + xa.z + xa.w) + (xb.x + xb.y + xb.z + xb.w)
             + (xc.x + xc.y + xc.z + xc.w) + (xd.x + xd.y + xd.z + xd.w);
    float s2 = xa.x * xa.x + xa.y * xa.y + xa.z * xa.z + xa.w * xa.w
             + xb.x * xb.x + xb.y * xb.y + xb.z * xb.z + xb.w * xb.w
             + xc.x * xc.x + xc.y * xc.y + xc.z * xc.z + xc.w * xc.w
             + xd.x * xd.x + xd.y * xd.y + xd.z * xd.z + xd.w * xd.w;
    #pragma unroll
    for (int o = 1; o <= 32; o <<= 1) s1 += __shfl_xor(s1, o);
    float h2 = s2;
    #pragma unroll
    for (int o = 1; o <= 16; o <<= 1) h2 += __shfl_xor(h2, o);
    const float oth = __shfl_xor(h2, 32);
    const float slo = (lane < 32) ? h2 : oth;
    const float shi = (lane < 32) ? oth : h2;
    const float mu = s1 * (1.0f / 1024.0f);
    const float var = (slo + shi) * (1.0f / 1024.0f) - mu * mu;
    const float rstd = rsqrtf(var + 1e-6f);
    const float imb = (slo - shi) * (1.0f / 512.0f) * (*bw_p);
    const float corr = (lane < 32) ? -imb : imb;
    const int i0 = lane * 16;
    const float4* wp = (const float4*)(w + i0);
    const float4* bp = (const float4*)(bvec + i0);
    const float4* gp = (const float4*)(gw + i0);
    float o16[16];
    float gd = 0.0f;
    #pragma unroll
    for (int q = 0; q < 4; ++q) {
        float4 xv = (q == 0) ? xa : (q == 1) ? xb : (q == 2) ? xc : xd;
        float4 wv = wp[q], bv = bp[q], gv = gp[q];
        float t0 = (xv.x - mu) * rstd * wv.x + bv.x + corr;
        float t1 = (xv.y - mu) * rstd * wv.y + bv.y + corr;
        float t2 = (xv.z - mu) * rstd * wv.z + bv.z + corr;
        float t3 = (xv.w - mu) * rstd * wv.w + bv.w + corr;
        gd += t0 * gv.x + t1 * gv.y + t2 * gv.z + t3 * gv.w;
        o16[4 * q + 0] = t0; o16[4 * q + 1] = t1; o16[4 * q + 2] = t2; o16[4 * q + 3] = t3;
    }
    #pragma unroll
    for (int o = 1; o <= 32; o <<= 1) gd += __shfl_xor(gd, o);
    if (lane == 0) G[row] = sigmoidf_(gd + *gb_p);
    u16 ob[16], pn[16];
    #pragma unroll
    for (int j = 0; j < 16; ++j) ob[j] = f2bf(o16[j]);
    #pragma unroll
    for (int j = 0; j < 8; ++j) {
        float px = o16[2 * j] + 1e-8f, py = o16[2 * j + 1] + 1e-8f;
        float rr = rsqrtf(px * px + py * py);
        pn[2 * j] = f2bf(px * rr); pn[2 * j + 1] = f2bf(py * rr);
    }
    *(uint4*)(OUT + (size_t)row * 1024 + i0) = *(uint4*)ob;
    *(uint4*)(OUT + (size_t)row * 1024 + i0 + 8) = *(uint4*)(ob + 8);
    *(uint4*)(PN + (size_t)row * 1024 + i0) = *(uint4*)pn;
    *(uint4*)(PN + (size_t)row * 1024 + i0 + 8) = *(uint4*)(pn + 8);
}

// ---------------------------------------------------------------------------
// weight fp32 -> bf16 (8 slots of 1M elements; order set by pointer args)
// ---------------------------------------------------------------------------
__global__ void __launch_bounds__(256) wconv_kernel(
    const float* w0, const float* w1, const float* w2, const float* w3,
    const float* w4, const float* w5, const float* w6, const float* w7,
    u16* __restrict__ dst)
{
    const float* s;
    switch (blockIdx.y) {
        case 0: s = w0; break; case 1: s = w1; break;
        case 2: s = w2; break; case 3: s = w3; break;
        case 4: s = w4; break; case 5: s = w5; break;
        case 6: s = w6; break; default: s = w7; break;
    }
    long i = (long)blockIdx.x * 1024 + threadIdx.x * 4;
    float4 v = *(const float4*)(s + i);
    u16 o[4] = { f2bf(v.x), f2bf(v.y), f2bf(v.z), f2bf(v.w) };
    *(uint2*)(dst + (long)blockIdx.y * 1048576 + i) = *(uint2*)o;
}

// ---------------------------------------------------------------------------
// FUSED FLASH ATTENTION (unchanged — verified passing).
// ---------------------------------------------------------------------------
__global__ void __launch_bounds__(256) attn_flash(
    const u16* __restrict__ Q, const u16* __restrict__ K,
    const u16* __restrict__ VT, const float* __restrict__ AG,
    const float* __restrict__ EG, u16* __restrict__ OC,
    int TQ, int TKV, long vbs)
{
    __shared__ __align__(16) u16 shm[21504];
    float* egf = (float*)(shm + 20480);
    const int t = threadIdx.x;
    const int lane = t & 63, w = t >> 6;
    const int l15 = lane & 15, g = lane >> 4;
    const int qt = blockIdx.x, h = blockIdx.y, b = blockIdx.z;
    const long qrow = (long)b * TQ + qt * 64 + w * 16 + l15;
    const u16* Qp = Q + qrow * 1024 + h * 64 + g * 8;
    const bf16x8 qf0 = *(const bf16x8*)(Qp);
    const bf16x8 qf1 = *(const bf16x8*)(Qp + 32);
    const u16* Kp = K + ((long)b * TKV + w * 16 + l15) * 1024 + h * 64 + g * 8;
    const u16* Vp = VT + (long)b * vbs + (long)(h * 64 + w * 16 + l15) * TKV + g * 8;
    const float* egp = EG + (long)b * TKV + lane;

    auto stage = [&](int kvt, int buf) {
        GLD(Kp + (long)kvt * 1024,      shm + buf * 4096 + (w * 2 + 0) * 512);
        GLD(Kp + (long)kvt * 1024 + 32, shm + buf * 4096 + (w * 2 + 1) * 512);
        GLD(Vp + kvt,      shm + 8192 + buf * 4096 + (w * 2 + 0) * 512);
        GLD(Vp + kvt + 32, shm + 8192 + buf * 4096 + (w * 2 + 1) * 512);
        GLD4(egp + kvt, egf + (buf * 4 + w) * 64);
    };

    const int nT = TKV >> 6;
    f32x4 O[4] = {};
    float mrun = -3.0e38f, lrun = 0.0f, serun = 0.0f;
    stage(0, 0);
    for (int i = 0; i < nT; ++i) {
        const int buf = i & 1;
        if (i + 1 < nT) {
            stage((i + 1) << 6, buf ^ 1);
            asm volatile("s_waitcnt vmcnt(5)" ::: "memory");
        } else {
            asm volatile("s_waitcnt vmcnt(0)" ::: "memory");
        }
        __builtin_amdgcn_sched_barrier(0);
        __builtin_amdgcn_s_barrier();
        const u16* kb = shm + buf * 4096;
        const u16* vb = shm + 8192 + buf * 4096;
        f32x4 sa[4] = {};
        #pragma unroll
        for (int kvf = 0; kvf < 4; ++kvf) {
            bf16x8 kf = *(const bf16x8*)(kb + (kvf * 2 + 0) * 512 + lane * 8);
            sa[kvf] = __builtin_amdgcn_mfma_f32_16x16x32_bf16(kf, qf0, sa[kvf], 0, 0, 0);
        }
        #pragma unroll
        for (int kvf = 0; kvf < 4; ++kvf) {
            bf16x8 kf = *(const bf16x8*)(kb + (kvf * 2 + 1) * 512 + lane * 8);
            sa[kvf] = __builtin_amdgcn_mfma_f32_16x16x32_bf16(kf, qf1, sa[kvf], 0, 0, 0);
        }
        float ev[4][4];
        float tmax = -3.0e38f;
        #pragma unroll
        for (int kvf = 0; kvf < 4; ++kvf)
            #pragma unroll
            for (int j = 0; j < 4; ++j) {
                float s = sa[kvf][j] * 0.125f;
                ev[kvf][j] = s;
                tmax = fmaxf(tmax, s);
            }
        tmax = fmaxf(tmax, __shfl_xor(tmax, 16));
        tmax = fmaxf(tmax, __shfl_xor(tmax, 32));
        const float mnew = fmaxf(mrun, tmax);
        const float corr = __expf(mrun - mnew);
        mrun = mnew;
        float suml = 0.0f, sumg = 0.0f;
        unsigned pk[4][2];
        #pragma unroll
        for (int kvf = 0; kvf < 4; ++kvf) {
            float4 eg4 = *(const float4*)(egf + (buf * 4 + w) * 64 + kvf * 16 + 4 * g);
            float e0 = __expf(ev[kvf][0] - mnew);
            float e1 = __expf(ev[kvf][1] - mnew);
            float e2 = __expf(ev[kvf][2] - mnew);
            float e3 = __expf(ev[kvf][3] - mnew);
            suml += (e0 + e1) + (e2 + e3);
            float g0 = e0 * eg4.x, g1 = e1 * eg4.y, g2 = e2 * eg4.z, g3 = e3 * eg4.w;
            sumg += (g0 + g1) + (g2 + g3);
            pk[kvf][0] = (unsigned)f2bf(g0) | ((unsigned)f2bf(g1) << 16);
            pk[kvf][1] = (unsigned)f2bf(g2) | ((unsigned)f2bf(g3) << 16);
        }
        suml += __shfl_xor(suml, 16); suml += __shfl_xor(suml, 32);
        sumg += __shfl_xor(sumg, 16); sumg += __shfl_xor(sumg, 32);
        lrun = lrun * corr + suml;
        serun = serun * corr + sumg;
        #pragma unroll
        for (int fd = 0; fd < 4; ++fd)
            #pragma unroll
            for (int j = 0; j < 4; ++j) O[fd][j] *= corr;
        u16* pw = shm + 16384 + w * 1024;
        #pragma unroll
        for (int kvf = 0; kvf < 4; ++kvf) {
            const int base = (kvf >> 1) * 512
                           + (l15 + 16 * (2 * (kvf & 1) + (g >> 1))) * 8
                           + 4 * (g & 1);
            *(unsigned*)(pw + base) = pk[kvf][0];
            *(unsigned*)(pw + base + 2) = pk[kvf][1];
        }
        #pragma unroll
        for (int ksv = 0; ksv < 2; ++ksv) {
            bf16x8 pf = *(const bf16x8*)(pw + ksv * 512 + lane * 8);
            #pragma unroll
            for (int fd = 0; fd < 4; ++fd) {
                bf16x8 vf = *(const bf16x8*)(vb + (fd * 2 + ksv) * 512 + lane * 8);
                O[fd] = __builtin_amdgcn_mfma_f32_16x16x32_bf16(vf, pf, O[fd], 0, 0, 0);
            }
        }
        if (i + 1 < nT) __builtin_amdgcn_s_barrier();
    }
    const float agv = AG[qrow];
    const float fac = agv / (agv * serun + lrun * 1e-8f);
    __syncthreads();
    u16* tw = shm + w * 1152;
    #pragma unroll
    for (int fd = 0; fd < 4; ++fd) {
        const int d0 = fd * 16 + 4 * g;
        unsigned v01 = (unsigned)f2bf(O[fd][0] * fac) | ((unsigned)f2bf(O[fd][1] * fac) << 16);
        unsigned v23 = (unsigned)f2bf(O[fd][2] * fac) | ((unsigned)f2bf(O[fd][3] * fac) << 16);
        *(unsigned*)(tw + l15 * 72 + d0) = v01;
        *(unsigned*)(tw + l15 * 72 + d0 + 2) = v23;
    }
    const int qr = lane >> 2, part = lane & 3;
    uint4 va = *(const uint4*)(tw + qr * 72 + part * 16);
    uint4 vb2 = *(const uint4*)(tw + qr * 72 + part * 16 + 8);
    u16* op = OC + ((long)b * TQ + qt * 64 + w * 16 + qr) * 1024 + h * 64 + part * 16;
    *(uint4*)(op) = va;
    *(uint4*)(op + 8) = vb2;
}

// ---------------------------------------------------------------------------
// mfma8: 256xBN bf16 NT GEMM, ring-3, ONE barrier per K-step, NO hand lgkmcnt:
// {reads (plain loads) | stage(i+2) | MFMA (compiler interleaves lgkmcnt
// with MFMA issue -> LDS latency hidden) | counted vmcnt | barrier}.
// Safety: every fragment is consumed by an MFMA before the barrier (data dep
// => reads complete pre-barrier); a buffer is re-staged only in the NEXT
// iteration, after that barrier. sched_barrier(0) pins reads below barriers.
// EPI 3: f32 base[idx]+acc*rs[row]
// EPI 6: micro fused 3-way (Kc bf16 | VTc transposed uint2 | Qe bf16)
// ---------------------------------------------------------------------------
template<int BN, int EPI>
__global__ void __launch_bounds__(512, (BN == 128) ? 4 : 1) mfma8(
    const u16* __restrict__ A, const u16* __restrict__ B,
    void* __restrict__ C, void* __restrict__ Cx, void* __restrict__ Cy,
    int K, int lda, int ldb,
    const float* __restrict__ base, const float* __restrict__ rs)
{
    constexpr int NR = BN / 64;
    constexpr int RSTRIDE = 8192 + BN * 32;
    __shared__ __align__(16) u16 sh[3 * RSTRIDE];
    const int gx = gridDim.x, gy = gridDim.y;
    const int lin = blockIdx.x + gx * blockIdx.y;
    const int xcd = lin & 7, off = lin >> 3;
    const int lby = gy >> 3;
    const int by = xcd * lby + (off % lby);
    const int bx = off / lby;
    const int t = threadIdx.x;
    const int lane = t & 63, w = t >> 6;
    const int wm = w >> 2, wn = w & 3;
    const long m0 = (long)by * 256;
    const long n0 = (long)bx * BN;
    const int frow = lane & 15, fk = (lane >> 4) * 8;
    const u16* Ag0 = A + (m0 + w * 16 + frow) * lda + fk;
    const u16* Ag1 = Ag0 + 128L * lda;
    const u16* Bg0 = B + (n0 + w * 16 + frow) * ldb + fk;
    const u16* Bg1 = Bg0 + 128L * ldb;

    auto stage = [&](int i, int r) {
        const int k0 = i << 5;
        u16* d = sh + r * RSTRIDE;
        GLD(Ag0 + k0, d + w * 512);
        GLD(Ag1 + k0, d + (8 + w) * 512);
        GLD(Bg0 + k0, d + 8192 + w * 512);
        if constexpr (BN == 256) GLD(Bg1 + k0, d + 8192 + (8 + w) * 512);
    };

    const int nIter = K >> 5;
    f32x4 acc[8][NR] = {};
    stage(0, 0);
    stage(1, 1);
    if constexpr (BN == 256) asm volatile("s_waitcnt vmcnt(4)" ::: "memory");
    else                     asm volatile("s_waitcnt vmcnt(3)" ::: "memory");
    __builtin_amdgcn_sched_barrier(0);
    __builtin_amdgcn_s_barrier();
    __builtin_amdgcn_sched_barrier(0);
    int r = 0;
    for (int i = 0; i < nIter; ++i) {
        const u16* ra = sh + r * RSTRIDE;
        bf16x8 af[8], bf[NR];
        #pragma unroll
        for (int mi = 0; mi < 8; ++mi)
            af[mi] = *(const bf16x8*)(ra + (wm * 8 + mi) * 512 + lane * 8);
        #pragma unroll
        for (int ni = 0; ni < NR; ++ni)
            bf[ni] = *(const bf16x8*)(ra + 8192 + (wn * NR + ni) * 512 + lane * 8);
        if (i + 2 < nIter) {
            int r2 = r + 2; if (r2 >= 3) r2 -= 3;
            stage(i + 2, r2);
        }
        // NO lgkmcnt here: compiler interleaves per-fragment waits with MFMAs.
        __builtin_amdgcn_s_setprio(1);
        #pragma unroll
        for (int mi = 0; mi < 8; ++mi)
            #pragma unroll
            for (int ni = 0; ni < NR; ++ni)
                acc[mi][ni] = __builtin_amdgcn_mfma_f32_16x16x32_bf16(af[mi], bf[ni], acc[mi][ni], 0, 0, 0);
        __builtin_amdgcn_s_setprio(0);
        if (i + 1 < nIter) {
            if (i + 2 < nIter) {
                if constexpr (BN == 256) asm volatile("s_waitcnt vmcnt(4)" ::: "memory");
                else                     asm volatile("s_waitcnt vmcnt(3)" ::: "memory");
            } else {
                asm volatile("s_waitcnt vmcnt(0)" ::: "memory");
            }
            __builtin_amdgcn_sched_barrier(0);
            __builtin_amdgcn_s_barrier();
            __builtin_amdgcn_sched_barrier(0);
        }
        ++r; if (r >= 3) r = 0;
    }
    // ---- epilogue ----
    const int l15 = lane & 15, l4 = lane >> 4;
    #pragma unroll
    for (int mi = 0; mi < 8; ++mi) {
        #pragma unroll
        for (int ni = 0; ni < NR; ++ni) {
            const long grow0 = m0 + wm * 128 + mi * 16 + l4 * 4;
            const long gcol  = n0 + wn * (BN / 4) + ni * 16 + l15;
            if constexpr (EPI == 3) {
                #pragma unroll
                for (int j = 0; j < 4; ++j) {
                    const long idx = (grow0 + j) * 1024 + gcol;
                    ((float*)C)[idx] = base[idx] + acc[mi][ni][j] * rs[grow0 + j];
                }
            } else {  // EPI == 6
                const int sec = (int)(n0 >> 10);
                if (sec == 0) {
                    #pragma unroll
                    for (int j = 0; j < 4; ++j)
                        ((u16*)C)[(grow0 + j) * 1024 + gcol] = f2bf(acc[mi][ni][j]);   // K_conv
                } else if (sec == 1) {
                    const long col = gcol - 1024;
                    u16 pk[4] = { f2bf(acc[mi][ni][0]), f2bf(acc[mi][ni][1]),
                                  f2bf(acc[mi][ni][2]), f2bf(acc[mi][ni][3]) };
                    const long idx = (grow0 >> 11) * 2097152 + col * 2048 + (grow0 & 2047);
                    *(uint2*)&((u16*)Cx)[idx] = *(uint2*)pk;                            // VT_conv
                } else {
                    #pragma unroll
                    for (int j = 0; j < 4; ++j)
                        ((u16*)Cy)[(grow0 + j) * 1024 + (gcol - 2048)] = f2bf(acc[mi][ni][j]); // Q_emer
                }
            }
        }
    }
}

// ---------------------------------------------------------------------------
// bf16 NT MFMA GEMM, 128xBN tile, 256 threads, ring-3 (small GEMMs).
// EPI 5: resonance blend + scalar transposed write (round-11 proven form).
// ---------------------------------------------------------------------------
template<int BN, int EPI, bool SWZ>
__global__ void __launch_bounds__(256) mfma_nt(
    const u16* __restrict__ A, long zAb, long zAh,
    const u16* __restrict__ B, long zBb, long zBh,
    void* __restrict__ C, long zCb, long zCh,
    void* __restrict__ Cx, void* __restrict__ Cy,
    int K, int lda, int ldb, int ldc, float alpha, int nH, int nsplit,
    const float* __restrict__ base, const float* __restrict__ rs,
    const float* __restrict__ accB, float* __restrict__ OT,
    long zOT, int ldt)
{
    constexpr int NR = BN / 32;
    constexpr int ABUF = 128 * 32;
    constexpr int BBUF = BN * 32;
    __shared__ __align__(16) u16 sh[3 * (ABUF + BBUF)];
    u16* const Ab0 = sh;
    u16* const Bb0 = sh + 3 * ABUF;
    int bx, by, bz;
    if constexpr (SWZ) {
        const int gx = gridDim.x, gy = gridDim.y;
        const int lin = blockIdx.x + gx * blockIdx.y;
        const int xcd = lin & 7, c = lin >> 3;
        const int LBY = gy >> 3;
        const int SPB = 4 * LBY;
        const int sc = c / SPB, rr = c - sc * SPB;
        const int byl = rr >> 2, bxl = rr & 3;
        by = xcd * LBY + byl;
        bx = sc * 4 + bxl;
        bz = 0;
    } else {
        bx = blockIdx.x; by = blockIdx.y; bz = blockIdx.z;
    }
    const int t = threadIdx.x;
    const int lane = t & 63, w = t >> 6;
    const int wr = w >> 1, wc = w & 1;
    const int slab = bz / nsplit, ks = bz - slab * nsplit;
    const int b = slab / nH, h = slab - b * nH;
    const int kchunk = K / nsplit;
    const int kbeg = ks * kchunk, kend = kbeg + kchunk;
    const long m0 = (long)by * 128;
    const long n0 = (long)bx * BN;
    const int frow = lane & 15, fko = (lane >> 4) * 8;
    const u16* gaA = A + zAb * b + zAh * h + (m0 + 32 * w + frow) * lda + fko;
    const u16* gbB;
    if constexpr (BN == 128) gbB = B + zBb * b + zBh * h + (n0 + 32 * w + frow) * ldb + fko;
    else                     gbB = B + zBb * b + zBh * h + (n0 + 16 * w + frow) * ldb + fko;

    auto stage = [&](int kk, int p) {
        u16* ap = Ab0 + p * ABUF;
        u16* bp = Bb0 + p * BBUF;
        GLD(gaA + kk, ap + 2 * w * 512);
        GLD(gaA + 16L * lda + kk, ap + (2 * w + 1) * 512);
        if constexpr (BN == 128) {
            GLD(gbB + kk, bp + 2 * w * 512);
            GLD(gbB + 16L * ldb + kk, bp + (2 * w + 1) * 512);
        } else {
            GLD(gbB + kk, bp + w * 512);
        }
    };

    const int nIter = (kend - kbeg) >> 5;
    f32x4 acc[4][NR] = {};
    stage(kbeg, 0);
    if (nIter > 1) stage(kbeg + 32, 1);
    int cur = 0;
    for (int i = 0; i < nIter; ++i) {
        if (i + 2 < nIter) {
            int p2 = cur + 2; if (p2 >= 3) p2 -= 3;
            stage(kbeg + (i + 2) * 32, p2);
            if constexpr (BN == 128) asm volatile("s_waitcnt vmcnt(8)" ::: "memory");
            else                     asm volatile("s_waitcnt vmcnt(6)" ::: "memory");
        } else if (i + 1 < nIter) {
            if constexpr (BN == 128) asm volatile("s_waitcnt vmcnt(4)" ::: "memory");
            else                     asm volatile("s_waitcnt vmcnt(3)" ::: "memory");
        } else {
            asm volatile("s_waitcnt vmcnt(0)" ::: "memory");
        }
        __builtin_amdgcn_sched_barrier(0);
        __builtin_amdgcn_s_barrier();
        __builtin_amdgcn_sched_barrier(0);
        const u16* ap = Ab0 + cur * ABUF;
        const u16* bp = Bb0 + cur * BBUF;
        bf16x8 af[4], bfr[NR];
        #pragma unroll
        for (int m = 0; m < 4; ++m)
            af[m] = *(const bf16x8*)(ap + (wr * 4 + m) * 512 + lane * 8);
        #pragma unroll
        for (int n = 0; n < NR; ++n)
            bfr[n] = *(const bf16x8*)(bp + (wc * NR + n) * 512 + lane * 8);
        asm volatile("s_waitcnt lgkmcnt(0)" ::: "memory");
        __builtin_amdgcn_sched_barrier(0);
        __builtin_amdgcn_s_barrier();
        #pragma unroll
        for (int m = 0; m < 4; ++m)
            #pragma unroll
            for (int n = 0; n < NR; ++n)
                acc[m][n] = __builtin_amdgcn_mfma_f32_16x16x32_bf16(af[m], bfr[n], acc[m][n], 0, 0, 0);
        cur = (cur == 2) ? 0 : cur + 1;
    }
    const long Coff = zCb * b + zCh * h;
    const int l15 = lane & 15, l4 = lane >> 4;
    #pragma unroll
    for (int m = 0; m < 4; ++m) {
        #pragma unroll
        for (int n = 0; n < NR; ++n) {
            #pragma unroll
            for (int j = 0; j < 4; ++j) {
                const long grow = m0 + wr * 64 + m * 16 + l4 * 4 + j;
                const long gcol = n0 + wc * (BN / 2) + n * 16 + l15;
                const float v = acc[m][n][j] * alpha;
                if constexpr (EPI == 3) {
                    const long idx = grow * ldc + gcol;
                    ((float*)C)[idx] = base[idx] + v * rs[grow];
                } else if constexpr (EPI == 5) {
                    const long idx = Coff + grow * ldc + gcol;
                    ((float*)C)[idx] = 0.7f * base[idx] + 0.3f * v;
                    const long tidx = zOT * b + gcol * (long)ldt + grow;
                    OT[tidx] = 0.7f * accB[tidx] + 0.3f * v;
                } else if constexpr (EPI == 7) {
                    const int sec = (int)(n0 >> 10);
                    if (sec == 0) ((u16*)C)[grow * 1024 + gcol] = f2bf(v);            // Q_conv
                    else if (sec == 1) ((u16*)Cx)[grow * 1024 + (gcol - 1024)] = f2bf(v); // K_emer
                    else {
                        const long col = gcol - 2048;                                  // VT_emer
                        ((u16*)Cy)[(grow >> 8) * 262144 + col * 256 + (grow & 255)] = f2bf(v);
                    }
                }
            }
        }
    }
}

__global__ void __launch_bounds__(256) rowmean_sig_kernel(
    const float* __restrict__ X, int len, float invlen,
    const float* __restrict__ alpha_p, float* __restrict__ OUT)
{
    const int row = blockIdx.x * 4 + (threadIdx.x >> 6);
    const int lane = threadIdx.x & 63;
    const float* xr = X + (long)row * len;
    float s = 0.0f;
    for (int k = lane; k < len; k += 64) s += xr[k];
    for (int o = 32; o > 0; o >>= 1) s += __shfl_xor(s, o);
    if (lane == 0) OUT[row] = sigmoidf_((*alpha_p) * s * invlen);
}

#define MFMA_TAIL nullptr, nullptr, nullptr, nullptr, 0L, 0

extern "C" void kernel_launch(void* const* d_in, const int* in_sizes, int n_in,
                              void* d_out, int out_size, void* d_ws, size_t ws_size,
                              hipStream_t stream)
{
    (void)in_sizes; (void)n_in; (void)out_size; (void)ws_size;
    const float* o_micro    = (const float*)d_in[0];
    const float* o_macro    = (const float*)d_in[1];
    const float* r_conv_acc = (const float*)d_in[2];
    const float* r_emer_acc = (const float*)d_in[3];
    const float* ln_u_w = (const float*)d_in[4];
    const float* ln_u_b = (const float*)d_in[5];
    const float* bw_u   = (const float*)d_in[6];
    const float* ln_m_w = (const float*)d_in[7];
    const float* ln_m_b = (const float*)d_in[8];
    const float* bw_m   = (const float*)d_in[9];
    const float* gu_w   = (const float*)d_in[10];
    const float* gu_b   = (const float*)d_in[11];
    const float* gm_w   = (const float*)d_in[12];
    const float* gm_b   = (const float*)d_in[13];
    const float* wq_c   = (const float*)d_in[14];
    const float* wk_c   = (const float*)d_in[15];
    const float* wv_c   = (const float*)d_in[16];
    const float* wo_c   = (const float*)d_in[17];
    const float* wq_e   = (const float*)d_in[18];
    const float* wk_e   = (const float*)d_in[19];
    const float* wv_e   = (const float*)d_in[20];
    const float* wo_e   = (const float*)d_in[21];
    const float* res_alpha = (const float*)d_in[22];

    float* out = (float*)d_out;
    float* out_micro = out;              // (4,2048,1024)
    float* out_macro = out + 8388608;    // (4,256,1024)
    float* out_rconv = out + 9437184;    // (4,256,2048)
    float* out_remer = out + 11534336;   // (4,2048,256)

    // workspace (f32 slot offsets; bf16 buffers use 2 el/slot)
    float* ws = (float*)d_ws;
    u16* OUb = (u16*)ws;                       // 8388608 bf16 (normed micro)
    u16* OMb = (u16*)(ws + 4194304);           // 1048576 bf16 (normed macro)
    u16* WB  = (u16*)(ws + 4718592);           // 8 x 1048576 bf16 weights
                                               //   [wk_c wv_c wq_e | wq_c wk_e wv_e | wo_c wo_e]
    u16* Kcb = (u16*)(ws + 8912896);           // conv K (8192x1024) -> later CTe
    u16* VTc = (u16*)(ws + 13107200);          // conv V^T [b][h][64][2048]
    u16* Qeb = (u16*)(ws + 17301504);          // emer Q (8192x1024)
    u16* Qcb = (u16*)(ws + 21495808);          // conv Q (1024x1024)
    u16* Keb = (u16*)(ws + 22020096);          // emer K (1024x1024)
    u16* VTe = (u16*)(ws + 22544384);          // emer V^T [b][h][64][256]
    u16* PNu = (u16*)(ws + 23068672);          // pairnormed micro (8.4M bf16)
    float* CT = ws + 27262976;                 // early: PNm; later conv ctx bf16
    float* GU = ws + 28311552;                 // 8192
    float* GM = GU + 8192;                     // 1024
    float* RCS = GM + 1024;                    // 1024
    float* RES = RCS + 1024;                   // 8192
    u16* PNm = (u16*)CT;
    u16* CTc = (u16*)CT;                       // conv ctx bf16 (1024x1024)
    u16* CTe = Kcb;                            // emer ctx bf16 (8192x1024)

    // 1. weights -> bf16, reordered for fused projections
    wconv_kernel<<<dim3(1024, 8), 256, 0, stream>>>(wk_c, wv_c, wq_e, wq_c, wk_e, wv_e, wo_c, wo_e, WB);
    // 2. balance norms + gates + fused pairnorm (wave-per-row)
    norm_gate_kernel<<<2048, 256, 0, stream>>>(o_micro, ln_u_w, ln_u_b, bw_u, gu_w, gu_b, OUb, PNu, GU);
    norm_gate_kernel<<<256, 256, 0, stream>>>(o_macro, ln_m_w, ln_m_b, bw_m, gm_w, gm_b, OMb, PNm, GM);
    // 3. resonance GEMM + 0.7/0.3 blend + transposed write
    mfma_nt<128, 5, false><<<dim3(16, 2, 4), 256, 0, stream>>>(
        PNm, 262144L, 0L, PNu, 2097152L, 0L, out_rconv, 524288L, 0L, nullptr, nullptr,
        1024, 1024, 1024, 2048, 1.0f / 512.0f, 1, 1,
        r_conv_acc, nullptr, r_emer_acc, out_remer, 524288L, 256);
    // 4. resonance scalars
    rowmean_sig_kernel<<<256, 256, 0, stream>>>(out_rconv, 2048, 1.0f / 2048.0f, res_alpha, RCS);
    rowmean_sig_kernel<<<2048, 256, 0, stream>>>(out_remer, 256, 1.0f / 256.0f, res_alpha, RES);
    // 5. fused micro-side projections: [K_conv | VT_conv | Q_emer]  (compiler-scheduled lgkm)
    mfma8<256, 6><<<dim3(12, 32), 512, 0, stream>>>(
        OUb, WB, Kcb, VTc, Qeb, 1024, 1024, 1024, nullptr, nullptr);
    // 6. fused macro-side projections: [Q_conv | K_emer | VT_emer]
    mfma_nt<128, 7, true><<<dim3(24, 8, 1), 256, 0, stream>>>(
        OMb, 0L, 0L, WB + 3 * 1048576, 0L, 0L, Qcb, 0L, 0L, Keb, VTe,
        1024, 1024, 1024, 1024, 1.0f, 1, 1, MFMA_TAIL);
    // 7. conv fused flash attention (q from macro, kv from micro)
    attn_flash<<<dim3(4, 16, 4), 256, 0, stream>>>(
        Qcb, Kcb, VTc, GM, GU, CTc, 256, 2048, 2097152L);
    // 8. conv out-proj + residual + r_conv_scalar -> o_macro_new
    mfma_nt<128, 3, false><<<dim3(8, 8, 1), 256, 0, stream>>>(
        CTc, 0L, 0L, WB + 6 * 1048576, 0L, 0L, out_macro, 0L, 0L, nullptr, nullptr,
        1024, 1024, 1024, 1024, 1.0f, 1, 1, o_macro, RCS, nullptr, nullptr, 0L, 0);
    // 9. emer fused flash attention (q from micro, kv from macro)
    attn_flash<<<dim3(32, 16, 4), 256, 0, stream>>>(
        Qeb, Keb, VTe, GU, GM, CTe, 2048, 256, 262144L);
    // 10. emer out-proj + residual + r_emer_scalar -> o_micro_new
    mfma8<128, 3><<<dim3(8, 32), 512, 0, stream>>>(
        CTe, WB + 7 * 1048576, out_micro, nullptr, nullptr,
        1024, 1024, 1024, o_micro, RES);
}